// Round 5
// baseline (1572.492 us; speedup 1.0000x reference)
//
#include <hip/hip_runtime.h>
#include <hip/hip_bf16.h>

// BloodFlowSkinAnalyzer. d_out is FLOAT32 (ref outputs f32), flat concat:
//   flow[4]@0, sync[4]@4, color[4*64*3]@8, masks[4,64,1,128,128]@776,
//   naturalness[4]@4195080, temporal[4,32,64]@4195084  (total 4203276)
// Inputs are f32 (detected; detectors kept for robustness).
// ws usage: colsum[512][4] floats only.

#define B2F(x) __bfloat162float(x)
#define NAT_OFF  4195080
#define TF_OFF   4195084

__device__ __forceinline__ float LDM(const void* p, int i, int mode) {
    return mode ? ((const float*)p)[i] : B2F(((const __hip_bfloat16*)p)[i]);
}

// face uniform[0,1): bf16 u16s have sign=0 and value<=0x3F80; f32 low halves
// are ~uniform -> ~75% flagged. mode=1 -> f32.
__device__ __forceinline__ int detect_mode_face(const void* face, int tid) {
    const unsigned short* u = (const unsigned short*)face;
    unsigned short v = u[2 * tid];
    int flagged = ((v & 0x8000u) || ((v & 0x7FFFu) > 0x3F80u)) ? 1 : 0;
    return __syncthreads_count(flagged) > 16 ? 1 : 0;
}

// weights ~N(0,0.05): bf16 exponent byte in [96,130]; f32 low halves uniform
// -> ~86% outside. mode=1 -> f32.
__device__ __forceinline__ int detect_mode_w(const void* w, int tid) {
    const unsigned short* u = (const unsigned short*)w;
    int nz = 0, impl = 0;
    if (tid < 64) {
        unsigned short v = u[2 * tid];
        if (v != 0) {
            nz = 1;
            int e = (v >> 7) & 0xFF;
            impl = (e < 96 || e > 130) ? 1 : 0;
        }
    }
    int nzc = __syncthreads_count(nz);
    int imc = __syncthreads_count(impl);
    return (2 * imc > nzc) ? 1 : 0;
}

// seg conv1(3->32,k3,p1)+conv2(32->16,k3,p1)+conv3(16->1,k1)+sigmoid + masked
// sums. One block = half an image (32 of 64 16x16 tiles), grid 512.
__global__ __launch_bounds__(256) void seg_kernel(
    const void* __restrict__ x,
    const void* __restrict__ w1p, const void* __restrict__ b1p,
    const void* __restrict__ w2p, const void* __restrict__ b2p,
    const void* __restrict__ w3p, const void* __restrict__ b3p,
    float* __restrict__ colsum, float* __restrict__ out)
{
    const int tid = threadIdx.x;
    const int img = blockIdx.x >> 1, half = blockIdx.x & 1;

    __shared__ float w1s[864];      // [oc][ic*9+k]
    __shared__ float b1s[32];
    __shared__ float w2s[4608];     // transposed: [(ic*9+k)*16 + oc]
    __shared__ float b2s[16];
    __shared__ float w3s[17];       // 16 weights + bias
    __shared__ float in_s[1200];    // 3 x 20 x 20 halo tile
    __shared__ float h1_s[16 * 342];// 16 ch x 18 x (stride 19)
    __shared__ float red[4][4];

    const int mode  = detect_mode_face(x, tid);
    const int wmode = detect_mode_w(w1p, tid);

    for (int i = tid; i < 864; i += 256) w1s[i] = LDM(w1p, i, wmode);
    if (tid < 32) b1s[tid] = LDM(b1p, tid, wmode);
    for (int i = tid; i < 4608; i += 256) {
        int oc = i / 288, r = i - oc * 288;      // r = ic*9 + k
        w2s[r * 16 + oc] = LDM(w2p, i, wmode);
    }
    if (tid < 16) b2s[tid] = LDM(b2p, tid, wmode);
    if (tid < 16) w3s[tid] = LDM(w3p, tid, wmode);
    if (tid == 0) w3s[16] = LDM(b3p, 0, wmode);

    float s0 = 0.f, s1 = 0.f, s2 = 0.f, sm = 0.f;
    const int i = tid >> 4, j = tid & 15;

    for (int tt = 0; tt < 32; ++tt) {
        const int tile = half * 32 + tt;
        const int r0 = (tile >> 3) * 16, c0 = (tile & 7) * 16;
        __syncthreads();   // in_s/h1_s safe to overwrite; weights staged (iter 0)

        // ---- stage 20x20x3 input halo ----
        if (mode) {
            const float* xf = (const float*)x + (size_t)img * 3 * 16384;
            for (int idx = tid; idx < 1200; idx += 256) {
                int ic = idx / 400, rem = idx - ic * 400;
                int r = rem / 20, cc = rem - r * 20;
                int gr = r0 - 2 + r, gc = c0 - 2 + cc;
                float vv = 0.f;
                if ((unsigned)gr < 128u && (unsigned)gc < 128u)
                    vv = xf[ic * 16384 + gr * 128 + gc];
                in_s[idx] = vv;
            }
        } else {
            const __hip_bfloat16* xb = (const __hip_bfloat16*)x + (size_t)img * 3 * 16384;
            for (int idx = tid; idx < 1200; idx += 256) {
                int ic = idx / 400, rem = idx - ic * 400;
                int r = rem / 20, cc = rem - r * 20;
                int gr = r0 - 2 + r, gc = c0 - 2 + cc;
                float vv = 0.f;
                if ((unsigned)gr < 128u && (unsigned)gc < 128u)
                    vv = B2F(xb[ic * 16384 + gr * 128 + gc]);
                in_s[idx] = vv;
            }
        }
        __syncthreads();

        float acc[16];
#pragma unroll
        for (int o = 0; o < 16; ++o) acc[o] = b2s[o];

        for (int g = 0; g < 2; ++g) {
            if (g) __syncthreads();          // conv2(g=0) reads done before overwrite
            // ---- conv1 group g: 16 output channels over 18x18 halo'd outputs
            for (int p = tid; p < 324; p += 256) {
                int hy = p / 18, hx = p - hy * 18;
                float xr[27];
#pragma unroll
                for (int ic = 0; ic < 3; ++ic)
#pragma unroll
                    for (int ky = 0; ky < 3; ++ky)
#pragma unroll
                        for (int kx = 0; kx < 3; ++kx)
                            xr[ic * 9 + ky * 3 + kx] = in_s[ic * 400 + (hy + ky) * 20 + hx + kx];
                bool valid = ((unsigned)(r0 - 1 + hy) < 128u) && ((unsigned)(c0 - 1 + hx) < 128u);
#pragma unroll 4
                for (int oc = 0; oc < 16; ++oc) {
                    float a = b1s[g * 16 + oc];
#pragma unroll
                    for (int q = 0; q < 27; ++q) a = fmaf(xr[q], w1s[(g * 16 + oc) * 27 + q], a);
                    h1_s[oc * 342 + hy * 19 + hx] = valid ? fmaxf(a, 0.f) : 0.f;
                }
            }
            __syncthreads();
            // ---- conv2 partial over this ic group (per output pixel) ----
            for (int ic = 0; ic < 16; ++ic) {
                const float* hb = &h1_s[ic * 342 + i * 19 + j];
                const float* wb = &w2s[(g * 16 + ic) * 144];
#pragma unroll
                for (int ky = 0; ky < 3; ++ky)
#pragma unroll
                    for (int kx = 0; kx < 3; ++kx) {
                        float v = hb[ky * 19 + kx];
                        const float* wp = wb + (ky * 3 + kx) * 16;
#pragma unroll
                        for (int o = 0; o < 16; ++o) acc[o] = fmaf(v, wp[o], acc[o]);
                    }
            }
        }
        // ---- conv3 + sigmoid + write + masked sums ----
        float m3 = w3s[16];
#pragma unroll
        for (int o = 0; o < 16; ++o) m3 = fmaf(fmaxf(acc[o], 0.f), w3s[o], m3);
        float mask = 1.f / (1.f + __expf(-m3));
        out[776 + (size_t)img * 16384 + (size_t)(r0 + i) * 128 + (size_t)(c0 + j)] = mask;

        float f0 = in_s[0 * 400 + (i + 2) * 20 + (j + 2)];
        float f1v = in_s[1 * 400 + (i + 2) * 20 + (j + 2)];
        float f2v = in_s[2 * 400 + (i + 2) * 20 + (j + 2)];
        s0 = fmaf(mask, f0, s0);
        s1 = fmaf(mask, f1v, s1);
        s2 = fmaf(mask, f2v, s2);
        sm += mask;
    }

    // ---- block reduction of the 4 sums ----
#pragma unroll
    for (int off = 32; off > 0; off >>= 1) {
        s0 += __shfl_down(s0, off);
        s1 += __shfl_down(s1, off);
        s2 += __shfl_down(s2, off);
        sm += __shfl_down(sm, off);
    }
    int wid = tid >> 6, lane = tid & 63;
    if (lane == 0) { red[wid][0] = s0; red[wid][1] = s1; red[wid][2] = s2; red[wid][3] = sm; }
    __syncthreads();
    if (tid < 4) {
        float s = red[0][tid] + red[1][tid] + red[2][tid] + red[3][tid];
        colsum[(size_t)blockIdx.x * 4 + tid] = s;   // [img][half][4]
    }
}

// Tail: color signals, ct convs, ta convs, pooling, FC, stats. 1 block / b.
__global__ __launch_bounds__(256) void tail_kernel(
    const void* __restrict__ face, const float* __restrict__ colsum,
    const void* cw1, const void* cb1, const void* cw2, const void* cb2,
    const void* cw3, const void* cb3,
    const void* tw1, const void* tb1, const void* tw2, const void* tb2,
    const void* tw3, const void* tb3,
    const void* fw1, const void* fb1, const void* fw2, const void* fb2,
    const void* fw3, const void* fb3,
    float* __restrict__ out)
{
    const int b = blockIdx.x, tid = threadIdx.x;
    __shared__ float tmp[64][4];
    __shared__ float cs_s[3 * 64];
    __shared__ float e3s[3 * 64];
    __shared__ float f1[32 * 64];
    __shared__ float f2[64 * 64];
    __shared__ float tf[32 * 64];
    __shared__ float wA[6144];
    __shared__ float pooled[32], g1[64], g2[32], sca[8];

    const int mode = detect_mode_face(face, tid);

    // 1. per-(b,t) sums from the two half-image partials
    {
        int t = tid >> 2, slot = tid & 3;
        int base = (b * 64 + t) * 8;
        tmp[t][slot] = colsum[base + slot] + colsum[base + 4 + slot];
    }
    __syncthreads();
    for (int idx = tid; idx < 192; idx += 256) {
        int c = idx >> 6, t = idx & 63;
        float v = tmp[t][c] / (tmp[t][3] + 1e-8f);
        cs_s[idx] = v;
        out[8 + (b * 64 + t) * 3 + c] = v;
    }
    __syncthreads();

    // 2. color_transformer (all k1)
    if (tid < 64) {
        int t = tid;
        float c0v = cs_s[t], c1v = cs_s[64 + t], c2v = cs_s[128 + t];
        float e1[16];
#pragma unroll
        for (int o = 0; o < 16; ++o)
            e1[o] = fmaxf(LDM(cb1, o, mode) + LDM(cw1, o * 3 + 0, mode) * c0v
                                            + LDM(cw1, o * 3 + 1, mode) * c1v
                                            + LDM(cw1, o * 3 + 2, mode) * c2v, 0.f);
        float e2[8];
#pragma unroll
        for (int o = 0; o < 8; ++o) {
            float a = LDM(cb2, o, mode);
#pragma unroll
            for (int i2 = 0; i2 < 16; ++i2) a += LDM(cw2, o * 16 + i2, mode) * e1[i2];
            e2[o] = fmaxf(a, 0.f);
        }
#pragma unroll
        for (int o = 0; o < 3; ++o) {
            float a = LDM(cb3, o, mode);
#pragma unroll
            for (int i2 = 0; i2 < 8; ++i2) a += LDM(cw3, o * 8 + i2, mode) * e2[i2];
            e3s[o * 64 + t] = a;   // no relu on last ct conv
        }
    }
    __syncthreads();

    // 3. ta1: 3->32 k3 p1; stage ta_w2 into LDS
    for (int idx = tid; idx < 2048; idx += 256) {
        int o = idx >> 6, t = idx & 63;
        float a = LDM(tb1, o, mode);
#pragma unroll
        for (int ic = 0; ic < 3; ++ic)
#pragma unroll
            for (int k = 0; k < 3; ++k) {
                int ttk = t + k - 1;
                if ((unsigned)ttk < 64u) a += e3s[ic * 64 + ttk] * LDM(tw1, (o * 3 + ic) * 3 + k, mode);
            }
        f1[idx] = fmaxf(a, 0.f);
    }
    for (int i2 = tid; i2 < 6144; i2 += 256) wA[i2] = LDM(tw2, i2, mode);
    __syncthreads();

    // 4. ta2: 32->64 k3 p1
    for (int idx = tid; idx < 4096; idx += 256) {
        int o = idx >> 6, t = idx & 63;
        float a = LDM(tb2, o, mode);
        for (int ic = 0; ic < 32; ++ic) {
            const float* wp = &wA[(o * 32 + ic) * 3];
            int base = ic * 64 + t;
            if (t > 0)  a += f1[base - 1] * wp[0];
            a += f1[base] * wp[1];
            if (t < 63) a += f1[base + 1] * wp[2];
        }
        f2[idx] = fmaxf(a, 0.f);
    }
    __syncthreads();
    for (int i2 = tid; i2 < 6144; i2 += 256) wA[i2] = LDM(tw3, i2, mode);
    __syncthreads();

    // 5. ta3: 64->32 k3 p1 (+ temporal_features out)
    for (int idx = tid; idx < 2048; idx += 256) {
        int o = idx >> 6, t = idx & 63;
        float a = LDM(tb3, o, mode);
        for (int ic = 0; ic < 64; ++ic) {
            const float* wp = &wA[(o * 64 + ic) * 3];
            int base = ic * 64 + t;
            if (t > 0)  a += f2[base - 1] * wp[0];
            a += f2[base] * wp[1];
            if (t < 63) a += f2[base + 1] * wp[2];
        }
        float r = fmaxf(a, 0.f);
        tf[idx] = r;
        out[TF_OFF + (b * 32 + o) * 64 + t] = r;
    }
    __syncthreads();

    // 6. pooled mean
    if (tid < 32) {
        float s = 0.f;
        for (int t = 0; t < 64; ++t) s += tf[tid * 64 + t];
        pooled[tid] = s * (1.f / 64.f);
    }
    __syncthreads();

    // 7. FC head
    if (tid < 64) {
        float a = LDM(fb1, tid, mode);
#pragma unroll
        for (int i2 = 0; i2 < 32; ++i2) a += pooled[i2] * LDM(fw1, tid * 32 + i2, mode);
        g1[tid] = fmaxf(a, 0.f);
    }
    __syncthreads();
    if (tid < 32) {
        float a = LDM(fb2, tid, mode);
        for (int i2 = 0; i2 < 64; ++i2) a += g1[i2] * LDM(fw2, tid * 64 + i2, mode);
        g2[tid] = fmaxf(a, 0.f);
    }
    __syncthreads();
    if (tid == 0) {
        float a = LDM(fb3, 0, mode);
        for (int i2 = 0; i2 < 32; ++i2) a += g2[i2] * LDM(fw3, i2, mode);
        float flow = 1.f / (1.f + expf(-a));
        sca[0] = flow;
        out[b] = flow;
    }
    // 8. per-channel std (ddof=1)
    if (tid >= 4 && tid < 7) {
        int c = tid - 4;
        float mu = 0.f;
        for (int t = 0; t < 64; ++t) mu += cs_s[c * 64 + t];
        mu *= (1.f / 64.f);
        float v = 0.f;
        for (int t = 0; t < 64; ++t) { float d = cs_s[c * 64 + t] - mu; v += d * d; }
        sca[1 + c] = sqrtf(v / 63.f);
    }
    __syncthreads();
    if (tid == 0) {
        float s0 = sca[1], s1 = sca[2], s2 = sca[3];
        float mu = (s0 + s1 + s2) * (1.f / 3.f);
        float var = ((s0 - mu) * (s0 - mu) + (s1 - mu) * (s1 - mu) + (s2 - mu) * (s2 - mu)) * 0.5f;
        float sy = 1.f / (1.f + expf(var));     // sigmoid(-var)
        out[4 + b] = sy;
        out[NAT_OFF + b] = (sca[0] + sy) * 0.5f;
    }
}

extern "C" void kernel_launch(void* const* d_in, const int* in_sizes, int n_in,
                              void* d_out, int out_size, void* d_ws, size_t ws_size,
                              hipStream_t stream)
{
    float* colsum = (float*)d_ws;                // 2048 floats only
    float* out = (float*)d_out;

    seg_kernel<<<dim3(512), 256, 0, stream>>>(d_in[0],
        d_in[1], d_in[2], d_in[3], d_in[4], d_in[5], d_in[6], colsum, out);

    tail_kernel<<<dim3(4), 256, 0, stream>>>(d_in[0], colsum,
        d_in[7],  d_in[8],  d_in[9],  d_in[10], d_in[11], d_in[12],
        d_in[13], d_in[14], d_in[15], d_in[16], d_in[17], d_in[18],
        d_in[19], d_in[20], d_in[21], d_in[22], d_in[23], d_in[24],
        out);
}

// Round 6
// 884.834 us; speedup vs baseline: 1.7772x; 1.7772x over previous
//
#include <hip/hip_runtime.h>
#include <hip/hip_bf16.h>

// BloodFlowSkinAnalyzer — all dtypes f32 (verified round 5: absmax 1.9e-9).
// Out layout (floats): flow[4]@0, sync[4]@4, color[4*64*3]@8,
//   masks[4,64,1,128,128]@776, naturalness[4]@4195080, temporal[4,32,64]@4195084
// ws layout (floats): colsum[4096][4] @0 (64KB) | w2T[4608] @16384 (18KB)

#define NAT_OFF  4195080
#define TF_OFF   4195084
#define W2T_OFF  16384

// Transpose seg_w2 [16oc][32ic][3][3] -> w2T[(ic*9+k)*16 + oc] for contiguous
// 16-wide scalar-load rows in seg_kernel.
__global__ __launch_bounds__(256) void prep_kernel(
    const float* __restrict__ w2, float* __restrict__ w2t)
{
    for (int i = threadIdx.x; i < 4608; i += 256) {
        int oc = i / 288, r = i - oc * 288;      // r = ic*9 + k
        w2t[r * 16 + oc] = w2[i];
    }
}

// Fused seg conv1(3->32,k3,p1)+conv2(32->16,k3,p1)+conv3(16->1,k1)+sigmoid
// + masked per-channel sums. One block = 4 of 64 16x16 tiles, grid 4096.
// Weights: global scalar loads (wave-uniform indices -> s_load, SGPR operands).
// LDS = 26.8KB -> 5 blocks/CU; 20 waves/CU.
__global__ __launch_bounds__(256) void seg_kernel(
    const float* __restrict__ x,
    const float* __restrict__ w1f, const float* __restrict__ b1f,
    const float* __restrict__ w2t, const float* __restrict__ b2f,
    const float* __restrict__ w3f, const float* __restrict__ b3f,
    float* __restrict__ colsum, float* __restrict__ out)
{
    const int tid  = threadIdx.x;
    const int img  = blockIdx.x >> 4;        // b*64+t
    const int part = blockIdx.x & 15;        // 4 tiles per part

    __shared__ float in_s[1200];             // 3 x 20 x 20 halo tile
    __shared__ float h1_s[16 * 342];         // 16 ch x 18 rows x (stride 19)
    __shared__ float red[4][4];

    const float* xin = x + (size_t)img * 3 * 16384;
    float s0 = 0.f, s1 = 0.f, s2 = 0.f, sm = 0.f;
    const int i = tid >> 4, j = tid & 15;

    for (int tt = 0; tt < 4; ++tt) {
        const int tile = part * 4 + tt;
        const int r0 = (tile >> 3) * 16, c0 = (tile & 7) * 16;
        __syncthreads();                     // prev-tile readers done

        // ---- stage 20x20x3 input halo ----
        for (int idx = tid; idx < 1200; idx += 256) {
            int ic = idx / 400, rem = idx - ic * 400;
            int r = rem / 20, cc = rem - r * 20;
            int gr = r0 - 2 + r, gc = c0 - 2 + cc;
            float vv = 0.f;
            if ((unsigned)gr < 128u && (unsigned)gc < 128u)
                vv = xin[ic * 16384 + gr * 128 + gc];
            in_s[idx] = vv;
        }
        __syncthreads();

        float acc[16];
#pragma unroll
        for (int o = 0; o < 16; ++o) acc[o] = b2f[o];

        for (int g = 0; g < 2; ++g) {
            if (g) __syncthreads();          // conv2(g=0) reads done before overwrite
            // ---- conv1 group g: 16 oc over 18x18 halo'd outputs ----
            for (int p = tid; p < 324; p += 256) {
                int hy = p / 18, hx = p - hy * 18;
                float xr[27];
#pragma unroll
                for (int ic = 0; ic < 3; ++ic)
#pragma unroll
                    for (int ky = 0; ky < 3; ++ky)
#pragma unroll
                        for (int kx = 0; kx < 3; ++kx)
                            xr[ic * 9 + ky * 3 + kx] = in_s[ic * 400 + (hy + ky) * 20 + hx + kx];
                bool valid = ((unsigned)(r0 - 1 + hy) < 128u) && ((unsigned)(c0 - 1 + hx) < 128u);
#pragma unroll 4
                for (int oc = 0; oc < 16; ++oc) {
                    float a = b1f[g * 16 + oc];
                    const float* wr = w1f + (g * 16 + oc) * 27;
#pragma unroll
                    for (int q = 0; q < 27; ++q) a = fmaf(xr[q], wr[q], a);
                    h1_s[oc * 342 + hy * 19 + hx] = valid ? fmaxf(a, 0.f) : 0.f;
                }
            }
            __syncthreads();
            // ---- conv2 partial over this 16-ic group (per output pixel) ----
            for (int ic = 0; ic < 16; ++ic) {
                const float* hb = &h1_s[ic * 342 + i * 19 + j];
                const float* wb = w2t + ((g * 16 + ic) * 9) * 16;
#pragma unroll
                for (int ky = 0; ky < 3; ++ky)
#pragma unroll
                    for (int kx = 0; kx < 3; ++kx) {
                        float v = hb[ky * 19 + kx];
                        const float* wp = wb + (ky * 3 + kx) * 16;
#pragma unroll
                        for (int o = 0; o < 16; ++o) acc[o] = fmaf(v, wp[o], acc[o]);
                    }
            }
        }
        // ---- conv3 + sigmoid + write + masked sums ----
        float m3 = b3f[0];
#pragma unroll
        for (int o = 0; o < 16; ++o) m3 = fmaf(fmaxf(acc[o], 0.f), w3f[o], m3);
        float mask = 1.f / (1.f + __expf(-m3));
        out[776 + (size_t)img * 16384 + (size_t)(r0 + i) * 128 + (size_t)(c0 + j)] = mask;

        float f0 = in_s[0 * 400 + (i + 2) * 20 + (j + 2)];
        float f1v = in_s[1 * 400 + (i + 2) * 20 + (j + 2)];
        float f2v = in_s[2 * 400 + (i + 2) * 20 + (j + 2)];
        s0 = fmaf(mask, f0, s0);
        s1 = fmaf(mask, f1v, s1);
        s2 = fmaf(mask, f2v, s2);
        sm += mask;
    }

    // ---- block reduction of the 4 sums ----
#pragma unroll
    for (int off = 32; off > 0; off >>= 1) {
        s0 += __shfl_down(s0, off);
        s1 += __shfl_down(s1, off);
        s2 += __shfl_down(s2, off);
        sm += __shfl_down(sm, off);
    }
    int wid = tid >> 6, lane = tid & 63;
    if (lane == 0) { red[wid][0] = s0; red[wid][1] = s1; red[wid][2] = s2; red[wid][3] = sm; }
    __syncthreads();
    if (tid < 4) {
        float s = red[0][tid] + red[1][tid] + red[2][tid] + red[3][tid];
        colsum[(size_t)blockIdx.x * 4 + tid] = s;   // [img][part][4]
    }
}

// Tail: color signals, ct convs, ta convs, pooling, FC, stats. 1 block / b.
__global__ __launch_bounds__(256) void tail_kernel(
    const float* __restrict__ colsum,
    const float* __restrict__ cw1, const float* __restrict__ cb1,
    const float* __restrict__ cw2, const float* __restrict__ cb2,
    const float* __restrict__ cw3, const float* __restrict__ cb3,
    const float* __restrict__ tw1, const float* __restrict__ tb1,
    const float* __restrict__ tw2, const float* __restrict__ tb2,
    const float* __restrict__ tw3, const float* __restrict__ tb3,
    const float* __restrict__ fw1, const float* __restrict__ fb1,
    const float* __restrict__ fw2, const float* __restrict__ fb2,
    const float* __restrict__ fw3, const float* __restrict__ fb3,
    float* __restrict__ out)
{
    const int b = blockIdx.x, tid = threadIdx.x;
    __shared__ float tmp[64][4];
    __shared__ float cs_s[3 * 64];
    __shared__ float e3s[3 * 64];
    __shared__ float f1[32 * 64];
    __shared__ float f2[64 * 64];
    __shared__ float tf[32 * 64];
    __shared__ float wA[6144];
    __shared__ float pooled[32], g1[64], g2[32], sca[8];

    // 1. per-(b,t) sums from the 16 per-part partials
    {
        int t = tid >> 2, slot = tid & 3;
        const float* pp = colsum + (size_t)((b * 64 + t) * 16) * 4 + slot;
        float s = 0.f;
#pragma unroll
        for (int p = 0; p < 16; ++p) s += pp[p * 4];
        tmp[t][slot] = s;
    }
    __syncthreads();
    for (int idx = tid; idx < 192; idx += 256) {
        int c = idx >> 6, t = idx & 63;
        float v = tmp[t][c] / (tmp[t][3] + 1e-8f);
        cs_s[idx] = v;
        out[8 + (b * 64 + t) * 3 + c] = v;
    }
    __syncthreads();

    // 2. color_transformer (all k1)
    if (tid < 64) {
        int t = tid;
        float c0v = cs_s[t], c1v = cs_s[64 + t], c2v = cs_s[128 + t];
        float e1[16];
#pragma unroll
        for (int o = 0; o < 16; ++o)
            e1[o] = fmaxf(cb1[o] + cw1[o * 3 + 0] * c0v + cw1[o * 3 + 1] * c1v
                                 + cw1[o * 3 + 2] * c2v, 0.f);
        float e2[8];
#pragma unroll
        for (int o = 0; o < 8; ++o) {
            float a = cb2[o];
#pragma unroll
            for (int i2 = 0; i2 < 16; ++i2) a += cw2[o * 16 + i2] * e1[i2];
            e2[o] = fmaxf(a, 0.f);
        }
#pragma unroll
        for (int o = 0; o < 3; ++o) {
            float a = cb3[o];
#pragma unroll
            for (int i2 = 0; i2 < 8; ++i2) a += cw3[o * 8 + i2] * e2[i2];
            e3s[o * 64 + t] = a;   // no relu on last ct conv
        }
    }
    __syncthreads();

    // 3. ta1: 3->32 k3 p1; stage ta_w2 into LDS
    for (int idx = tid; idx < 2048; idx += 256) {
        int o = idx >> 6, t = idx & 63;
        float a = tb1[o];
#pragma unroll
        for (int ic = 0; ic < 3; ++ic)
#pragma unroll
            for (int k = 0; k < 3; ++k) {
                int ttk = t + k - 1;
                if ((unsigned)ttk < 64u) a += e3s[ic * 64 + ttk] * tw1[(o * 3 + ic) * 3 + k];
            }
        f1[idx] = fmaxf(a, 0.f);
    }
    for (int i2 = tid; i2 < 6144; i2 += 256) wA[i2] = tw2[i2];
    __syncthreads();

    // 4. ta2: 32->64 k3 p1
    for (int idx = tid; idx < 4096; idx += 256) {
        int o = idx >> 6, t = idx & 63;
        float a = tb2[o];
        for (int ic = 0; ic < 32; ++ic) {
            const float* wp = &wA[(o * 32 + ic) * 3];
            int base = ic * 64 + t;
            if (t > 0)  a += f1[base - 1] * wp[0];
            a += f1[base] * wp[1];
            if (t < 63) a += f1[base + 1] * wp[2];
        }
        f2[idx] = fmaxf(a, 0.f);
    }
    __syncthreads();
    for (int i2 = tid; i2 < 6144; i2 += 256) wA[i2] = tw3[i2];
    __syncthreads();

    // 5. ta3: 64->32 k3 p1 (+ temporal_features out)
    for (int idx = tid; idx < 2048; idx += 256) {
        int o = idx >> 6, t = idx & 63;
        float a = tb3[o];
        for (int ic = 0; ic < 64; ++ic) {
            const float* wp = &wA[(o * 64 + ic) * 3];
            int base = ic * 64 + t;
            if (t > 0)  a += f2[base - 1] * wp[0];
            a += f2[base] * wp[1];
            if (t < 63) a += f2[base + 1] * wp[2];
        }
        float r = fmaxf(a, 0.f);
        tf[idx] = r;
        out[TF_OFF + (b * 32 + o) * 64 + t] = r;
    }
    __syncthreads();

    // 6. pooled mean
    if (tid < 32) {
        float s = 0.f;
        for (int t = 0; t < 64; ++t) s += tf[tid * 64 + t];
        pooled[tid] = s * (1.f / 64.f);
    }
    __syncthreads();

    // 7. FC head
    if (tid < 64) {
        float a = fb1[tid];
#pragma unroll
        for (int i2 = 0; i2 < 32; ++i2) a += pooled[i2] * fw1[tid * 32 + i2];
        g1[tid] = fmaxf(a, 0.f);
    }
    __syncthreads();
    if (tid < 32) {
        float a = fb2[tid];
        for (int i2 = 0; i2 < 64; ++i2) a += g1[i2] * fw2[tid * 64 + i2];
        g2[tid] = fmaxf(a, 0.f);
    }
    __syncthreads();
    if (tid == 0) {
        float a = fb3[0];
        for (int i2 = 0; i2 < 32; ++i2) a += g2[i2] * fw3[i2];
        float flow = 1.f / (1.f + expf(-a));
        sca[0] = flow;
        out[b] = flow;
    }
    // 8. per-channel std (ddof=1)
    if (tid >= 4 && tid < 7) {
        int c = tid - 4;
        float mu = 0.f;
        for (int t = 0; t < 64; ++t) mu += cs_s[c * 64 + t];
        mu *= (1.f / 64.f);
        float v = 0.f;
        for (int t = 0; t < 64; ++t) { float d = cs_s[c * 64 + t] - mu; v += d * d; }
        sca[1 + c] = sqrtf(v / 63.f);
    }
    __syncthreads();
    if (tid == 0) {
        float s0 = sca[1], s1 = sca[2], s2 = sca[3];
        float mu = (s0 + s1 + s2) * (1.f / 3.f);
        float var = ((s0 - mu) * (s0 - mu) + (s1 - mu) * (s1 - mu) + (s2 - mu) * (s2 - mu)) * 0.5f;
        float sy = 1.f / (1.f + expf(var));     // sigmoid(-var)
        out[4 + b] = sy;
        out[NAT_OFF + b] = (sca[0] + sy) * 0.5f;
    }
}

extern "C" void kernel_launch(void* const* d_in, const int* in_sizes, int n_in,
                              void* d_out, int out_size, void* d_ws, size_t ws_size,
                              hipStream_t stream)
{
    float* wsf = (float*)d_ws;
    float* out = (float*)d_out;

    prep_kernel<<<1, 256, 0, stream>>>((const float*)d_in[3], wsf + W2T_OFF);

    seg_kernel<<<dim3(4096), 256, 0, stream>>>((const float*)d_in[0],
        (const float*)d_in[1], (const float*)d_in[2], wsf + W2T_OFF,
        (const float*)d_in[4], (const float*)d_in[5], (const float*)d_in[6],
        wsf, out);

    tail_kernel<<<dim3(4), 256, 0, stream>>>(wsf,
        (const float*)d_in[7],  (const float*)d_in[8],
        (const float*)d_in[9],  (const float*)d_in[10],
        (const float*)d_in[11], (const float*)d_in[12],
        (const float*)d_in[13], (const float*)d_in[14],
        (const float*)d_in[15], (const float*)d_in[16],
        (const float*)d_in[17], (const float*)d_in[18],
        (const float*)d_in[19], (const float*)d_in[20],
        (const float*)d_in[21], (const float*)d_in[22],
        (const float*)d_in[23], (const float*)d_in[24],
        out);
}

// Round 7
// 753.832 us; speedup vs baseline: 2.0860x; 1.1738x over previous
//
#include <hip/hip_runtime.h>
#include <hip/hip_bf16.h>

// BloodFlowSkinAnalyzer — f32 in/out (verified r5). Out layout (floats):
//   flow[4]@0, sync[4]@4, color[4*64*3]@8, masks[4,64,1,128,128]@776,
//   naturalness[4]@4195080, temporal[4,32,64]@4195084
// ws: colsum[4096][4] floats @0.
// conv2 (84% of FLOPs) runs on MFMA bf16 16x16x32; conv1 on VALU f32.

typedef __attribute__((ext_vector_type(8))) short bf16x8;
typedef __attribute__((ext_vector_type(4))) float f32x4;
typedef __attribute__((ext_vector_type(4))) unsigned int u32x4;

#define NAT_OFF  4195080
#define TF_OFF   4195084

__device__ __forceinline__ unsigned short f2bf(float f) {   // RNE f32->bf16
    unsigned u = __float_as_uint(f);
    u += 0x7FFFu + ((u >> 16) & 1u);
    return (unsigned short)(u >> 16);
}

// Fused seg: conv1(3->32,k3,p1) VALU + conv2(32->16,k3,p1) MFMA +
// conv3(16->1,k1)+sigmoid + masked sums. Block = 4 of 64 16x16 tiles.
__global__ __launch_bounds__(256) void seg_kernel(
    const float* __restrict__ x,
    const float* __restrict__ w1f, const float* __restrict__ b1f,
    const float* __restrict__ w2f, const float* __restrict__ b2f,
    const float* __restrict__ w3f, const float* __restrict__ b3f,
    float* __restrict__ colsum, float* __restrict__ out)
{
    const int tid  = threadIdx.x;
    const int lane = tid & 63;
    const int wid  = tid >> 6;
    const int img  = blockIdx.x >> 4;        // b*64+t
    const int part = blockIdx.x & 15;        // 4 tiles per part

    __shared__ float in_s[1200];                         // 3 x 20 x 20 f32 halo
    __shared__ __align__(16) unsigned short h1_s[12960]; // [(y*18+x)*40+ic] bf16
    __shared__ float red[4][4];

    const int ocl = lane & 15;   // free index: A-row (x-pos) and B-col (oc)
    const int g   = lane >> 4;   // k-group (8 ic's each)

    // ---- B-fragments: 9 chunks c=(ky*3+kx), k=ic; w2 is [oc][ic][3][3] ----
    bf16x8 bfrag[9];
#pragma unroll
    for (int c = 0; c < 9; ++c) {
        bf16x8 t;
#pragma unroll
        for (int e = 0; e < 8; ++e)
            t[e] = (short)f2bf(w2f[(ocl * 32 + g * 8 + e) * 9 + c]);
        bfrag[c] = t;
    }
    const float b2_l = b2f[ocl];
    const float w3_l = w3f[ocl];
    const float b3v  = b3f[0];

    const float* xin = x + (size_t)img * 3 * 16384;
    float s0 = 0.f, s1 = 0.f, s2 = 0.f, sm = 0.f;

    for (int tt = 0; tt < 4; ++tt) {
        const int tile = part * 4 + tt;
        const int r0 = (tile >> 3) * 16, c0 = (tile & 7) * 16;
        __syncthreads();                     // prev-tile readers done

        // ---- stage 20x20x3 input halo (f32) ----
        for (int idx = tid; idx < 1200; idx += 256) {
            int ic = idx / 400, rem = idx - ic * 400;
            int r = rem / 20, cc = rem - r * 20;
            int gr = r0 - 2 + r, gc = c0 - 2 + cc;
            float vv = 0.f;
            if ((unsigned)gr < 128u && (unsigned)gc < 128u)
                vv = xin[ic * 16384 + gr * 128 + gc];
            in_s[idx] = vv;
        }
        __syncthreads();

        // ---- conv1: 18x18 halo'd outputs, 32 oc, bf16-packed [y][x][ic] ----
        for (int p = tid; p < 324; p += 256) {
            int hy = p / 18, hx = p - hy * 18;
            float xr[27];
#pragma unroll
            for (int ic = 0; ic < 3; ++ic)
#pragma unroll
                for (int ky = 0; ky < 3; ++ky)
#pragma unroll
                    for (int kx = 0; kx < 3; ++kx)
                        xr[ic * 9 + ky * 3 + kx] = in_s[ic * 400 + (hy + ky) * 20 + hx + kx];
            bool valid = ((unsigned)(r0 - 1 + hy) < 128u) && ((unsigned)(c0 - 1 + hx) < 128u);
#pragma unroll
            for (int half = 0; half < 2; ++half) {
                unsigned pk[8];
#pragma unroll
                for (int oc = 0; oc < 16; ++oc) {
                    const float* wr = w1f + (half * 16 + oc) * 27;
                    float a = b1f[half * 16 + oc];
#pragma unroll
                    for (int q2 = 0; q2 < 27; ++q2) a = fmaf(xr[q2], wr[q2], a);
                    a = valid ? fmaxf(a, 0.f) : 0.f;
                    unsigned hb = (unsigned)f2bf(a);
                    if (oc & 1) pk[oc >> 1] |= hb << 16;
                    else        pk[oc >> 1]  = hb;
                }
                u32x4 u0 = {pk[0], pk[1], pk[2], pk[3]};
                u32x4 u1 = {pk[4], pk[5], pk[6], pk[7]};
                *reinterpret_cast<u32x4*>(&h1_s[p * 40 + half * 16])     = u0;
                *reinterpret_cast<u32x4*>(&h1_s[p * 40 + half * 16 + 8]) = u1;
            }
        }
        __syncthreads();

        // ---- conv2 MFMA + conv3 epilogue: wave wid owns rows wid*4..wid*4+3
        for (int q = 0; q < 4; ++q) {
            const int s = wid * 4 + q;       // output row within tile
            f32x4 acc = {0.f, 0.f, 0.f, 0.f};
#pragma unroll
            for (int c = 0; c < 9; ++c) {
                int ky = c / 3, kx = c - ky * 3;
                int off = ((s + ky) * 18 + (ocl + kx)) * 40 + g * 8;
                bf16x8 afrag = *reinterpret_cast<const bf16x8*>(&h1_s[off]);
                acc = __builtin_amdgcn_mfma_f32_16x16x32_bf16(afrag, bfrag[c], acc, 0, 0, 0);
            }
            // D: row(x) = g*4+reg, col(oc) = ocl  [m89-verified layout]
            float m0 = fmaxf(acc[0] + b2_l, 0.f) * w3_l;
            float m1 = fmaxf(acc[1] + b2_l, 0.f) * w3_l;
            float m2 = fmaxf(acc[2] + b2_l, 0.f) * w3_l;
            float m3 = fmaxf(acc[3] + b2_l, 0.f) * w3_l;
#pragma unroll
            for (int mk2 = 1; mk2 < 16; mk2 <<= 1) {      // reduce over 16 oc lanes
                m0 += __shfl_xor(m0, mk2);
                m1 += __shfl_xor(m1, mk2);
                m2 += __shfl_xor(m2, mk2);
                m3 += __shfl_xor(m3, mk2);
            }
            if (ocl < 4) {
                int r = lane & 3;
                float mm = (r == 0) ? m0 : (r == 1) ? m1 : (r == 2) ? m2 : m3;
                float msk = 1.f / (1.f + __expf(-(mm + b3v)));
                int xw = g * 4 + r;
                out[776 + (size_t)img * 16384 + (size_t)(r0 + s) * 128 + (c0 + xw)] = msk;
                float f0  = in_s[      (s + 2) * 20 + (xw + 2)];
                float f1v = in_s[400 + (s + 2) * 20 + (xw + 2)];
                float f2v = in_s[800 + (s + 2) * 20 + (xw + 2)];
                s0 = fmaf(msk, f0, s0);
                s1 = fmaf(msk, f1v, s1);
                s2 = fmaf(msk, f2v, s2);
                sm += msk;
            }
        }
    }

    // ---- block reduction of the 4 sums ----
#pragma unroll
    for (int off = 32; off > 0; off >>= 1) {
        s0 += __shfl_down(s0, off);
        s1 += __shfl_down(s1, off);
        s2 += __shfl_down(s2, off);
        sm += __shfl_down(sm, off);
    }
    if (lane == 0) { red[wid][0] = s0; red[wid][1] = s1; red[wid][2] = s2; red[wid][3] = sm; }
    __syncthreads();
    if (tid < 4) {
        float s = red[0][tid] + red[1][tid] + red[2][tid] + red[3][tid];
        colsum[(size_t)blockIdx.x * 4 + tid] = s;   // [img][part][4]
    }
}

// Tail: color signals, ct convs, ta convs, pooling, FC, stats. 1 block / b.
__global__ __launch_bounds__(256) void tail_kernel(
    const float* __restrict__ colsum,
    const float* __restrict__ cw1, const float* __restrict__ cb1,
    const float* __restrict__ cw2, const float* __restrict__ cb2,
    const float* __restrict__ cw3, const float* __restrict__ cb3,
    const float* __restrict__ tw1, const float* __restrict__ tb1,
    const float* __restrict__ tw2, const float* __restrict__ tb2,
    const float* __restrict__ tw3, const float* __restrict__ tb3,
    const float* __restrict__ fw1, const float* __restrict__ fb1,
    const float* __restrict__ fw2, const float* __restrict__ fb2,
    const float* __restrict__ fw3, const float* __restrict__ fb3,
    float* __restrict__ out)
{
    const int b = blockIdx.x, tid = threadIdx.x;
    __shared__ float tmp[64][4];
    __shared__ float cs_s[3 * 64];
    __shared__ float e3s[3 * 64];
    __shared__ float f1[32 * 64];
    __shared__ float f2[64 * 64];
    __shared__ float tf[32 * 64];
    __shared__ float wA[6144];
    __shared__ float pooled[32], g1[64], g2[32], sca[8];

    {
        int t = tid >> 2, slot = tid & 3;
        const float* pp = colsum + (size_t)((b * 64 + t) * 16) * 4 + slot;
        float s = 0.f;
#pragma unroll
        for (int p = 0; p < 16; ++p) s += pp[p * 4];
        tmp[t][slot] = s;
    }
    __syncthreads();
    for (int idx = tid; idx < 192; idx += 256) {
        int c = idx >> 6, t = idx & 63;
        float v = tmp[t][c] / (tmp[t][3] + 1e-8f);
        cs_s[idx] = v;
        out[8 + (b * 64 + t) * 3 + c] = v;
    }
    __syncthreads();

    if (tid < 64) {
        int t = tid;
        float c0v = cs_s[t], c1v = cs_s[64 + t], c2v = cs_s[128 + t];
        float e1[16];
#pragma unroll
        for (int o = 0; o < 16; ++o)
            e1[o] = fmaxf(cb1[o] + cw1[o * 3 + 0] * c0v + cw1[o * 3 + 1] * c1v
                                 + cw1[o * 3 + 2] * c2v, 0.f);
        float e2[8];
#pragma unroll
        for (int o = 0; o < 8; ++o) {
            float a = cb2[o];
#pragma unroll
            for (int i2 = 0; i2 < 16; ++i2) a += cw2[o * 16 + i2] * e1[i2];
            e2[o] = fmaxf(a, 0.f);
        }
#pragma unroll
        for (int o = 0; o < 3; ++o) {
            float a = cb3[o];
#pragma unroll
            for (int i2 = 0; i2 < 8; ++i2) a += cw3[o * 8 + i2] * e2[i2];
            e3s[o * 64 + t] = a;   // no relu on last ct conv
        }
    }
    __syncthreads();

    for (int idx = tid; idx < 2048; idx += 256) {
        int o = idx >> 6, t = idx & 63;
        float a = tb1[o];
#pragma unroll
        for (int ic = 0; ic < 3; ++ic)
#pragma unroll
            for (int k = 0; k < 3; ++k) {
                int ttk = t + k - 1;
                if ((unsigned)ttk < 64u) a += e3s[ic * 64 + ttk] * tw1[(o * 3 + ic) * 3 + k];
            }
        f1[idx] = fmaxf(a, 0.f);
    }
    for (int i2 = tid; i2 < 6144; i2 += 256) wA[i2] = tw2[i2];
    __syncthreads();

    for (int idx = tid; idx < 4096; idx += 256) {
        int o = idx >> 6, t = idx & 63;
        float a = tb2[o];
        for (int ic = 0; ic < 32; ++ic) {
            const float* wp = &wA[(o * 32 + ic) * 3];
            int base = ic * 64 + t;
            if (t > 0)  a += f1[base - 1] * wp[0];
            a += f1[base] * wp[1];
            if (t < 63) a += f1[base + 1] * wp[2];
        }
        f2[idx] = fmaxf(a, 0.f);
    }
    __syncthreads();
    for (int i2 = tid; i2 < 6144; i2 += 256) wA[i2] = tw3[i2];
    __syncthreads();

    for (int idx = tid; idx < 2048; idx += 256) {
        int o = idx >> 6, t = idx & 63;
        float a = tb3[o];
        for (int ic = 0; ic < 64; ++ic) {
            const float* wp = &wA[(o * 64 + ic) * 3];
            int base = ic * 64 + t;
            if (t > 0)  a += f2[base - 1] * wp[0];
            a += f2[base] * wp[1];
            if (t < 63) a += f2[base + 1] * wp[2];
        }
        float r = fmaxf(a, 0.f);
        tf[idx] = r;
        out[TF_OFF + (b * 32 + o) * 64 + t] = r;
    }
    __syncthreads();

    if (tid < 32) {
        float s = 0.f;
        for (int t = 0; t < 64; ++t) s += tf[tid * 64 + t];
        pooled[tid] = s * (1.f / 64.f);
    }
    __syncthreads();

    if (tid < 64) {
        float a = fb1[tid];
#pragma unroll
        for (int i2 = 0; i2 < 32; ++i2) a += pooled[i2] * fw1[tid * 32 + i2];
        g1[tid] = fmaxf(a, 0.f);
    }
    __syncthreads();
    if (tid < 32) {
        float a = fb2[tid];
        for (int i2 = 0; i2 < 64; ++i2) a += g1[i2] * fw2[tid * 64 + i2];
        g2[tid] = fmaxf(a, 0.f);
    }
    __syncthreads();
    if (tid == 0) {
        float a = fb3[0];
        for (int i2 = 0; i2 < 32; ++i2) a += g2[i2] * fw3[i2];
        float flow = 1.f / (1.f + expf(-a));
        sca[0] = flow;
        out[b] = flow;
    }
    if (tid >= 4 && tid < 7) {
        int c = tid - 4;
        float mu = 0.f;
        for (int t = 0; t < 64; ++t) mu += cs_s[c * 64 + t];
        mu *= (1.f / 64.f);
        float v = 0.f;
        for (int t = 0; t < 64; ++t) { float d = cs_s[c * 64 + t] - mu; v += d * d; }
        sca[1 + c] = sqrtf(v / 63.f);
    }
    __syncthreads();
    if (tid == 0) {
        float s0 = sca[1], s1 = sca[2], s2 = sca[3];
        float mu = (s0 + s1 + s2) * (1.f / 3.f);
        float var = ((s0 - mu) * (s0 - mu) + (s1 - mu) * (s1 - mu) + (s2 - mu) * (s2 - mu)) * 0.5f;
        float sy = 1.f / (1.f + expf(var));     // sigmoid(-var)
        out[4 + b] = sy;
        out[NAT_OFF + b] = (sca[0] + sy) * 0.5f;
    }
}

extern "C" void kernel_launch(void* const* d_in, const int* in_sizes, int n_in,
                              void* d_out, int out_size, void* d_ws, size_t ws_size,
                              hipStream_t stream)
{
    float* wsf = (float*)d_ws;
    float* out = (float*)d_out;

    seg_kernel<<<dim3(4096), 256, 0, stream>>>((const float*)d_in[0],
        (const float*)d_in[1], (const float*)d_in[2],
        (const float*)d_in[3], (const float*)d_in[4],
        (const float*)d_in[5], (const float*)d_in[6],
        wsf, out);

    tail_kernel<<<dim3(4), 256, 0, stream>>>(wsf,
        (const float*)d_in[7],  (const float*)d_in[8],
        (const float*)d_in[9],  (const float*)d_in[10],
        (const float*)d_in[11], (const float*)d_in[12],
        (const float*)d_in[13], (const float*)d_in[14],
        (const float*)d_in[15], (const float*)d_in[16],
        (const float*)d_in[17], (const float*)d_in[18],
        (const float*)d_in[19], (const float*)d_in[20],
        (const float*)d_in[21], (const float*)d_in[22],
        (const float*)d_in[23], (const float*)d_in[24],
        out);
}

// Round 8
// 314.086 us; speedup vs baseline: 5.0066x; 2.4001x over previous
//
#include <hip/hip_runtime.h>
#include <hip/hip_bf16.h>

// BloodFlowSkinAnalyzer — f32 in/out (verified r5). Out layout (floats):
//   flow[4]@0, sync[4]@4, color[4*64*3]@8, masks[4,64,1,128,128]@776,
//   naturalness[4]@4195080, temporal[4,32,64]@4195084
// ws: colsum[4096][4] floats @0.
// BOTH seg convs on MFMA bf16 16x16x32 (layouts HW-verified in r7):
//   A row = lane&15, k = (lane>>4)*8+e ; D row=(lane>>4)*4+reg, col=lane&15.

typedef __attribute__((ext_vector_type(8))) short bf16x8;
typedef __attribute__((ext_vector_type(4))) float f32x4;
typedef __attribute__((ext_vector_type(4))) unsigned int u32x4;

#define NAT_OFF  4195080
#define TF_OFF   4195084

__device__ __forceinline__ unsigned short f2bf(float f) {   // RNE f32->bf16
    unsigned u = __float_as_uint(f);
    u += 0x7FFFu + ((u >> 16) & 1u);
    return (unsigned short)(u >> 16);
}

// Fused seg: conv1(3->32,k3,p1) MFMA + conv2(32->16,k3,p1) MFMA +
// conv3(16->1,k1)+sigmoid + masked sums. Block = 4 of 64 16x16 tiles.
__global__ __launch_bounds__(256) void seg_kernel(
    const float* __restrict__ x,
    const float* __restrict__ w1f, const float* __restrict__ b1f,
    const float* __restrict__ w2f, const float* __restrict__ b2f,
    const float* __restrict__ w3f, const float* __restrict__ b3f,
    float* __restrict__ colsum, float* __restrict__ out)
{
    const int tid  = threadIdx.x;
    const int lane = tid & 63;
    const int wid  = tid >> 6;
    const int img  = blockIdx.x >> 4;        // b*64+t
    const int part = blockIdx.x & 15;        // 4 tiles per part

    __shared__ float in_s[1200];                         // 3 x 20 x 20 f32 halo
    __shared__ __align__(16) unsigned short h1_s[12960]; // [(y*18+x)*40+oc] bf16
    __shared__ float red[4][4];

    const int ocl = lane & 15;   // free idx: A-row / B-col
    const int g   = lane >> 4;   // k-group (8 k's each)

    // ---- conv1 B-frags (k = ic*9+ky*3+kx, w1 native [oc][k]); k>=27 -> 0.
    //      half0 -> oc = 2*ocl (even), half1 -> oc = 2*ocl+1 (odd).
    bf16x8 c1b0, c1b1;
    int offB[8];                 // per-lane LDS dword offsets for A gather
#pragma unroll
    for (int e = 0; e < 8; ++e) {
        int k = g * 8 + e;
        if (k < 27) {
            int ic = k / 9, r2 = k - ic * 9, ky = r2 / 3, kx = r2 - ky * 3;
            offB[e] = ic * 400 + ky * 20 + kx;
            c1b0[e] = (short)f2bf(w1f[(2 * ocl)     * 27 + k]);
            c1b1[e] = (short)f2bf(w1f[(2 * ocl + 1) * 27 + k]);
        } else {
            offB[e] = 0;
            c1b0[e] = 0; c1b1[e] = 0;
        }
    }
    const float b1_e = b1f[2 * ocl], b1_o = b1f[2 * ocl + 1];

    // ---- conv2 B-frags: 9 chunks c=(ky*3+kx), k=ic; w2 is [oc][ic][3][3] ----
    bf16x8 bfrag[9];
#pragma unroll
    for (int c = 0; c < 9; ++c) {
        bf16x8 t;
#pragma unroll
        for (int e = 0; e < 8; ++e)
            t[e] = (short)f2bf(w2f[(ocl * 32 + g * 8 + e) * 9 + c]);
        bfrag[c] = t;
    }
    const float b2_l = b2f[ocl];
    const float w3_l = w3f[ocl];
    const float b3v  = b3f[0];

    const float* xin = x + (size_t)img * 3 * 16384;
    float s0 = 0.f, s1 = 0.f, s2 = 0.f, sm = 0.f;

    for (int tt = 0; tt < 4; ++tt) {
        const int tile = part * 4 + tt;
        const int r0 = (tile >> 3) * 16, c0 = (tile & 7) * 16;
        __syncthreads();                     // prev-tile readers done

        // ---- stage 20x20x3 input halo (f32) ----
        for (int idx = tid; idx < 1200; idx += 256) {
            int ic = idx / 400, rem = idx - ic * 400;
            int r = rem / 20, cc = rem - r * 20;
            int gr = r0 - 2 + r, gc = c0 - 2 + cc;
            float vv = 0.f;
            if ((unsigned)gr < 128u && (unsigned)gc < 128u)
                vv = xin[ic * 16384 + gr * 128 + gc];
            in_s[idx] = vv;
        }
        __syncthreads();

        // ---- conv1 MFMA: 21 groups of 16 positions over 4 waves ----
        for (int grp = wid; grp < 21; grp += 4) {
            int pos = grp * 16 + ocl;                 // A row
            int hy = pos / 18, hx = pos - hy * 18;
            int base = hy * 20 + hx;
            base = base > 357 ? 357 : base;           // clamp tail-group lanes
            bf16x8 afrag;
#pragma unroll
            for (int e = 0; e < 8; ++e)
                afrag[e] = (short)f2bf(in_s[base + offB[e]]);
            f32x4 d0 = {0.f, 0.f, 0.f, 0.f}, d1 = {0.f, 0.f, 0.f, 0.f};
            d0 = __builtin_amdgcn_mfma_f32_16x16x32_bf16(afrag, c1b0, d0, 0, 0, 0);
            d1 = __builtin_amdgcn_mfma_f32_16x16x32_bf16(afrag, c1b1, d1, 0, 0, 0);
            // D rows = positions grp*16 + g*4 + r ; cols: oc 2*ocl / 2*ocl+1
            int p0 = grp * 16 + g * 4;
            int hy2 = p0 / 18, hx2 = p0 - hy2 * 18;
#pragma unroll
            for (int r = 0; r < 4; ++r) {
                int p2 = p0 + r;
                if (p2 < 324) {
                    bool valid = ((unsigned)(r0 - 1 + hy2) < 128u) &&
                                 ((unsigned)(c0 - 1 + hx2) < 128u);
                    float he = valid ? fmaxf(d0[r] + b1_e, 0.f) : 0.f;
                    float ho = valid ? fmaxf(d1[r] + b1_o, 0.f) : 0.f;
                    unsigned pk = (unsigned)f2bf(he) | ((unsigned)f2bf(ho) << 16);
                    *reinterpret_cast<unsigned*>(&h1_s[p2 * 40 + 2 * ocl]) = pk;
                }
                ++hx2;
                if (hx2 == 18) { hx2 = 0; ++hy2; }
            }
        }
        __syncthreads();

        // ---- conv2 MFMA + conv3 epilogue: wave wid owns rows wid*4..+3 ----
        for (int q = 0; q < 4; ++q) {
            const int s = wid * 4 + q;       // output row within tile
            f32x4 acc = {0.f, 0.f, 0.f, 0.f};
#pragma unroll
            for (int c = 0; c < 9; ++c) {
                int ky = c / 3, kx = c - ky * 3;
                int off = ((s + ky) * 18 + (ocl + kx)) * 40 + g * 8;
                bf16x8 afrag = *reinterpret_cast<const bf16x8*>(&h1_s[off]);
                acc = __builtin_amdgcn_mfma_f32_16x16x32_bf16(afrag, bfrag[c], acc, 0, 0, 0);
            }
            float m0 = fmaxf(acc[0] + b2_l, 0.f) * w3_l;
            float m1 = fmaxf(acc[1] + b2_l, 0.f) * w3_l;
            float m2 = fmaxf(acc[2] + b2_l, 0.f) * w3_l;
            float m3 = fmaxf(acc[3] + b2_l, 0.f) * w3_l;
#pragma unroll
            for (int mk2 = 1; mk2 < 16; mk2 <<= 1) {      // reduce over 16 oc lanes
                m0 += __shfl_xor(m0, mk2);
                m1 += __shfl_xor(m1, mk2);
                m2 += __shfl_xor(m2, mk2);
                m3 += __shfl_xor(m3, mk2);
            }
            if (ocl < 4) {
                int r = lane & 3;
                float mm = (r == 0) ? m0 : (r == 1) ? m1 : (r == 2) ? m2 : m3;
                float msk = 1.f / (1.f + __expf(-(mm + b3v)));
                int xw = g * 4 + r;
                out[776 + (size_t)img * 16384 + (size_t)(r0 + s) * 128 + (c0 + xw)] = msk;
                float f0  = in_s[      (s + 2) * 20 + (xw + 2)];
                float f1v = in_s[400 + (s + 2) * 20 + (xw + 2)];
                float f2v = in_s[800 + (s + 2) * 20 + (xw + 2)];
                s0 = fmaf(msk, f0, s0);
                s1 = fmaf(msk, f1v, s1);
                s2 = fmaf(msk, f2v, s2);
                sm += msk;
            }
        }
    }

    // ---- block reduction of the 4 sums ----
#pragma unroll
    for (int off = 32; off > 0; off >>= 1) {
        s0 += __shfl_down(s0, off);
        s1 += __shfl_down(s1, off);
        s2 += __shfl_down(s2, off);
        sm += __shfl_down(sm, off);
    }
    if (lane == 0) { red[wid][0] = s0; red[wid][1] = s1; red[wid][2] = s2; red[wid][3] = sm; }
    __syncthreads();
    if (tid < 4) {
        float s = red[0][tid] + red[1][tid] + red[2][tid] + red[3][tid];
        colsum[(size_t)blockIdx.x * 4 + tid] = s;   // [img][part][4]
    }
}

// Tail: color signals, ct convs, ta convs, pooling, FC, stats. 1 block / b.
__global__ __launch_bounds__(256) void tail_kernel(
    const float* __restrict__ colsum,
    const float* __restrict__ cw1, const float* __restrict__ cb1,
    const float* __restrict__ cw2, const float* __restrict__ cb2,
    const float* __restrict__ cw3, const float* __restrict__ cb3,
    const float* __restrict__ tw1, const float* __restrict__ tb1,
    const float* __restrict__ tw2, const float* __restrict__ tb2,
    const float* __restrict__ tw3, const float* __restrict__ tb3,
    const float* __restrict__ fw1, const float* __restrict__ fb1,
    const float* __restrict__ fw2, const float* __restrict__ fb2,
    const float* __restrict__ fw3, const float* __restrict__ fb3,
    float* __restrict__ out)
{
    const int b = blockIdx.x, tid = threadIdx.x;
    __shared__ float tmp[64][4];
    __shared__ float cs_s[3 * 64];
    __shared__ float e3s[3 * 64];
    __shared__ float f1[32 * 64];
    __shared__ float f2[64 * 64];
    __shared__ float tf[32 * 64];
    __shared__ float wA[6144];
    __shared__ float pooled[32], g1[64], g2[32], sca[8];

    {
        int t = tid >> 2, slot = tid & 3;
        const float* pp = colsum + (size_t)((b * 64 + t) * 16) * 4 + slot;
        float s = 0.f;
#pragma unroll
        for (int p = 0; p < 16; ++p) s += pp[p * 4];
        tmp[t][slot] = s;
    }
    __syncthreads();
    for (int idx = tid; idx < 192; idx += 256) {
        int c = idx >> 6, t = idx & 63;
        float v = tmp[t][c] / (tmp[t][3] + 1e-8f);
        cs_s[idx] = v;
        out[8 + (b * 64 + t) * 3 + c] = v;
    }
    __syncthreads();

    if (tid < 64) {
        int t = tid;
        float c0v = cs_s[t], c1v = cs_s[64 + t], c2v = cs_s[128 + t];
        float e1[16];
#pragma unroll
        for (int o = 0; o < 16; ++o)
            e1[o] = fmaxf(cb1[o] + cw1[o * 3 + 0] * c0v + cw1[o * 3 + 1] * c1v
                                 + cw1[o * 3 + 2] * c2v, 0.f);
        float e2[8];
#pragma unroll
        for (int o = 0; o < 8; ++o) {
            float a = cb2[o];
#pragma unroll
            for (int i2 = 0; i2 < 16; ++i2) a += cw2[o * 16 + i2] * e1[i2];
            e2[o] = fmaxf(a, 0.f);
        }
#pragma unroll
        for (int o = 0; o < 3; ++o) {
            float a = cb3[o];
#pragma unroll
            for (int i2 = 0; i2 < 8; ++i2) a += cw3[o * 8 + i2] * e2[i2];
            e3s[o * 64 + t] = a;   // no relu on last ct conv
        }
    }
    __syncthreads();

    for (int idx = tid; idx < 2048; idx += 256) {
        int o = idx >> 6, t = idx & 63;
        float a = tb1[o];
#pragma unroll
        for (int ic = 0; ic < 3; ++ic)
#pragma unroll
            for (int k = 0; k < 3; ++k) {
                int ttk = t + k - 1;
                if ((unsigned)ttk < 64u) a += e3s[ic * 64 + ttk] * tw1[(o * 3 + ic) * 3 + k];
            }
        f1[idx] = fmaxf(a, 0.f);
    }
    for (int i2 = tid; i2 < 6144; i2 += 256) wA[i2] = tw2[i2];
    __syncthreads();

    for (int idx = tid; idx < 4096; idx += 256) {
        int o = idx >> 6, t = idx & 63;
        float a = tb2[o];
        for (int ic = 0; ic < 32; ++ic) {
            const float* wp = &wA[(o * 32 + ic) * 3];
            int base = ic * 64 + t;
            if (t > 0)  a += f1[base - 1] * wp[0];
            a += f1[base] * wp[1];
            if (t < 63) a += f1[base + 1] * wp[2];
        }
        f2[idx] = fmaxf(a, 0.f);
    }
    __syncthreads();
    for (int i2 = tid; i2 < 6144; i2 += 256) wA[i2] = tw3[i2];
    __syncthreads();

    for (int idx = tid; idx < 2048; idx += 256) {
        int o = idx >> 6, t = idx & 63;
        float a = tb3[o];
        for (int ic = 0; ic < 64; ++ic) {
            const float* wp = &wA[(o * 64 + ic) * 3];
            int base = ic * 64 + t;
            if (t > 0)  a += f2[base - 1] * wp[0];
            a += f2[base] * wp[1];
            if (t < 63) a += f2[base + 1] * wp[2];
        }
        float r = fmaxf(a, 0.f);
        tf[idx] = r;
        out[TF_OFF + (b * 32 + o) * 64 + t] = r;
    }
    __syncthreads();

    if (tid < 32) {
        float s = 0.f;
        for (int t = 0; t < 64; ++t) s += tf[tid * 64 + t];
        pooled[tid] = s * (1.f / 64.f);
    }
    __syncthreads();

    if (tid < 64) {
        float a = fb1[tid];
#pragma unroll
        for (int i2 = 0; i2 < 32; ++i2) a += pooled[i2] * fw1[tid * 32 + i2];
        g1[tid] = fmaxf(a, 0.f);
    }
    __syncthreads();
    if (tid < 32) {
        float a = fb2[tid];
        for (int i2 = 0; i2 < 64; ++i2) a += g1[i2] * fw2[tid * 64 + i2];
        g2[tid] = fmaxf(a, 0.f);
    }
    __syncthreads();
    if (tid == 0) {
        float a = fb3[0];
        for (int i2 = 0; i2 < 32; ++i2) a += g2[i2] * fw3[i2];
        float flow = 1.f / (1.f + expf(-a));
        sca[0] = flow;
        out[b] = flow;
    }
    if (tid >= 4 && tid < 7) {
        int c = tid - 4;
        float mu = 0.f;
        for (int t = 0; t < 64; ++t) mu += cs_s[c * 64 + t];
        mu *= (1.f / 64.f);
        float v = 0.f;
        for (int t = 0; t < 64; ++t) { float d = cs_s[c * 64 + t] - mu; v += d * d; }
        sca[1 + c] = sqrtf(v / 63.f);
    }
    __syncthreads();
    if (tid == 0) {
        float s0 = sca[1], s1 = sca[2], s2 = sca[3];
        float mu = (s0 + s1 + s2) * (1.f / 3.f);
        float var = ((s0 - mu) * (s0 - mu) + (s1 - mu) * (s1 - mu) + (s2 - mu) * (s2 - mu)) * 0.5f;
        float sy = 1.f / (1.f + expf(var));     // sigmoid(-var)
        out[4 + b] = sy;
        out[NAT_OFF + b] = (sca[0] + sy) * 0.5f;
    }
}

extern "C" void kernel_launch(void* const* d_in, const int* in_sizes, int n_in,
                              void* d_out, int out_size, void* d_ws, size_t ws_size,
                              hipStream_t stream)
{
    float* wsf = (float*)d_ws;
    float* out = (float*)d_out;

    seg_kernel<<<dim3(4096), 256, 0, stream>>>((const float*)d_in[0],
        (const float*)d_in[1], (const float*)d_in[2],
        (const float*)d_in[3], (const float*)d_in[4],
        (const float*)d_in[5], (const float*)d_in[6],
        wsf, out);

    tail_kernel<<<dim3(4), 256, 0, stream>>>(wsf,
        (const float*)d_in[7],  (const float*)d_in[8],
        (const float*)d_in[9],  (const float*)d_in[10],
        (const float*)d_in[11], (const float*)d_in[12],
        (const float*)d_in[13], (const float*)d_in[14],
        (const float*)d_in[15], (const float*)d_in[16],
        (const float*)d_in[17], (const float*)d_in[18],
        (const float*)d_in[19], (const float*)d_in[20],
        (const float*)d_in[21], (const float*)d_in[22],
        (const float*)d_in[23], (const float*)d_in[24],
        out);
}